// Round 17
// baseline (157.743 us; speedup 1.0000x reference)
//
#include <hip/hip_runtime.h>
#include <math.h>
#include <stdint.h>
#include <stddef.h>

typedef __bf16 bf16_t;
typedef __bf16 bf16x8 __attribute__((ext_vector_type(8)));
typedef __bf16 bf16x4 __attribute__((ext_vector_type(4)));
typedef float f32x4 __attribute__((ext_vector_type(4)));

#define DEV __device__ __forceinline__

// ---------------------------------------------------------------- utilities

DEV void gload_lds16(const void* g, void* l) {
  __builtin_amdgcn_global_load_lds((__attribute__((address_space(1))) void*)g,
                                   (__attribute__((address_space(3))) void*)l,
                                   16, 0, 0);
}

template <bool MAXOP>
DEV float blockReduce256(float v, float* sm) {
  const int lane = threadIdx.x & 63, wid = threadIdx.x >> 6;
#pragma unroll
  for (int o = 32; o > 0; o >>= 1) {
    float ov = __shfl_down(v, o);
    v = MAXOP ? fmaxf(v, ov) : (v + ov);
  }
  if (lane == 0) sm[wid] = v;
  __syncthreads();
  float r = MAXOP ? fmaxf(fmaxf(sm[0], sm[1]), fmaxf(sm[2], sm[3]))
                  : (sm[0] + sm[1] + sm[2] + sm[3]);
  __syncthreads();
  return r;
}

// -------------------------------------------------- mega prep kernel
__global__ __launch_bounds__(256) void prep_kernel(
    const float* __restrict__ x, const float* __restrict__ ln1_w,
    const float* __restrict__ ln1_b, bf16_t* __restrict__ hbuf,
    const float* __restrict__ attn_w, bf16_t* __restrict__ attn_wT,
    const float* __restrict__ proj_w, bf16_t* __restrict__ proj_wT,
    const float* __restrict__ ff_w1, bf16_t* __restrict__ ff_w1T,
    const float* __restrict__ ff_w2, bf16_t* __restrict__ ff_w2T,
    const float* __restrict__ fk_w, bf16_t* __restrict__ fkT,
    const float* __restrict__ fv_w, bf16_t* __restrict__ fvT) {
  __shared__ float red[4];
  __shared__ float tile[32][33];
  const int tid = threadIdx.x;
  int bid = blockIdx.x;

  if (bid < 2048) {  // ---- LN1 row
    const float* row = x + (size_t)bid * 768;
    float v[3];
    float s = 0.f;
#pragma unroll
    for (int i = 0; i < 3; ++i) {
      v[i] = row[tid + i * 256];
      s += v[i];
    }
    s = blockReduce256<false>(s, red);
    const float mean = s * (1.f / 768.f);
    float s2 = 0.f;
#pragma unroll
    for (int i = 0; i < 3; ++i) {
      float d = v[i] - mean;
      s2 += d * d;
    }
    s2 = blockReduce256<false>(s2, red);
    const float rstd = rsqrtf(s2 * (1.f / 768.f) + 1e-5f);
#pragma unroll
    for (int i = 0; i < 3; ++i) {
      int c = tid + i * 256;
      hbuf[(size_t)bid * 768 + c] = (bf16_t)((v[i] - mean) * rstd * ln1_w[c] + ln1_b[c]);
    }
    return;
  }
  bid -= 2048;

  const float* in;
  bf16_t* outp;
  int ldin, ldout, R, C, bx, by;
  if (bid < 1728) {
    in = attn_w; outp = attn_wT; ldin = 2304; ldout = 768; R = 768; C = 2304;
    bx = bid % 72; by = bid / 72;
  } else if (bid < 2304) {
    int k = bid - 1728;
    in = proj_w; outp = proj_wT; ldin = 768; ldout = 768; R = 768; C = 768;
    bx = k % 24; by = k / 24;
  } else if (bid < 4608) {
    int k = bid - 2304;
    in = ff_w1; outp = ff_w1T; ldin = 3072; ldout = 768; R = 768; C = 3072;
    bx = k % 96; by = k / 96;
  } else if (bid < 6912) {
    int k = bid - 4608;
    in = ff_w2; outp = ff_w2T; ldin = 768; ldout = 3072; R = 3072; C = 768;
    bx = k % 24; by = k / 24;
  } else if (bid < 8448) {
    int k = bid - 6912;
    int z = k >> 7, r = k & 127;
    in = fk_w + (size_t)z * 64 * 2047; outp = fkT + (size_t)z * 2047 * 64;
    ldin = 2047; ldout = 64; R = 64; C = 2047;
    bx = r % 64; by = r / 64;
  } else {
    int k = bid - 8448;
    int z = k >> 7, r = k & 127;
    in = fv_w + (size_t)z * 2047 * 64; outp = fvT + (size_t)z * 64 * 2048;
    ldin = 64; ldout = 2048; R = 2047; C = 64;
    bx = r % 2; by = r / 2;
  }

  const int tx = tid & 31, ty = tid >> 5;
  const int c0 = bx * 32, r0 = by * 32;
#pragma unroll
  for (int i = 0; i < 4; ++i) {
    int r = r0 + ty + i * 8, c = c0 + tx;
    if (r < R && c < C) tile[ty + i * 8][tx] = in[(size_t)r * ldin + c];
  }
  __syncthreads();
#pragma unroll
  for (int i = 0; i < 4; ++i) {
    int orow = c0 + ty + i * 8, oc = r0 + tx;
    if (orow < C && oc < R) outp[(size_t)orow * ldout + oc] = (bf16_t)tile[tx][ty + i * 8];
  }
}

// ----------------------------------------- split-K reduce + residual + LN2
__global__ __launch_bounds__(256) void reduce_ln_kernel(
    const bf16_t* __restrict__ P, int KS, const float* __restrict__ x,
    const float* __restrict__ pb, float* __restrict__ x2,
    bf16_t* __restrict__ h2, const float* __restrict__ w,
    const float* __restrict__ b) {
  __shared__ float red[4];
  const int t = blockIdx.x, tid = threadIdx.x;
  float v[3];
  float s = 0.f;
#pragma unroll
  for (int i = 0; i < 3; ++i) {
    const int c = tid + i * 256;
    const size_t idx = (size_t)t * 768 + c;
    float a = x[idx] + pb[c];
    for (int ss = 0; ss < KS; ++ss) a += (float)P[(size_t)ss * 2048 * 768 + idx];
    v[i] = a;
    x2[idx] = a;
    s += a;
  }
  s = blockReduce256<false>(s, red);
  const float mean = s * (1.f / 768.f);
  float s2 = 0.f;
#pragma unroll
  for (int i = 0; i < 3; ++i) {
    float d = v[i] - mean;
    s2 += d * d;
  }
  s2 = blockReduce256<false>(s2, red);
  const float rstd = rsqrtf(s2 * (1.f / 768.f) + 1e-5f);
#pragma unroll
  for (int i = 0; i < 3; ++i) {
    int c = tid + i * 256;
    h2[(size_t)t * 768 + c] = (bf16_t)((v[i] - mean) * rstd * w[c] + b[c]);
  }
}

// ----------------------------------------- split-K reduce + residual (out)
__global__ __launch_bounds__(256) void reduce_out_kernel(
    const bf16_t* __restrict__ P, int KS, const float* __restrict__ x2,
    const float* __restrict__ bb, float* __restrict__ out) {
  const int t = blockIdx.x, tid = threadIdx.x;
#pragma unroll
  for (int i = 0; i < 3; ++i) {
    const int c = tid + i * 256;
    const size_t idx = (size_t)t * 768 + c;
    float a = x2[idx] + bb[c];
    for (int ss = 0; ss < KS; ++ss) a += (float)P[(size_t)ss * 2048 * 768 + idx];
    out[idx] = a;
  }
}

// ---------------------------------------------------------------- GEMM (B^T)
// BK=64 K-step, XOR-swizzled staging (rule #21), __syncthreads per step
// (r13-proven structure). Optional fused vT write for the qkv GEMM.
template <int WM, int WN, int EPIL, bool OBF16, bool VT>
__global__ __launch_bounds__(64 * WM * WN) void gemm_bt_kernel(
    const bf16_t* __restrict__ A, long long sAz, int lda,
    const bf16_t* __restrict__ Bt, long long sBz, int ldb,
    void* __restrict__ Cv, long long sCz, int ldc,
    const float* __restrict__ bias,
    const float* __restrict__ resid, long long sRz,
    bf16_t* __restrict__ vt,
    float alpha, int M, int N, int K) {
  constexpr int BM = WM * 64, BN = WN * 64;
  constexpr int NTHR = 64 * WM * WN;
  const int tid = threadIdx.x;
  const int lane = tid & 63, wid = tid >> 6;
  const int wr = wid / WN, wc = wid % WN;
  const int m0 = blockIdx.y * BM, n0 = blockIdx.x * BN;
  A += (long long)blockIdx.z * sAz;
  Bt += (long long)blockIdx.z * sBz;

  __shared__ alignas(16) bf16_t sA[2][BM * 64];
  __shared__ alignas(16) bf16_t sB[2][BN * 64];

  f32x4 acc[4][4] = {};

  auto stage = [&](int buf, int k0) {
#pragma unroll
    for (int it = 0; it < (BM * 8) / NTHR; ++it) {
      int c = it * NTHR + tid;
      int row = c >> 3, slot = c & 7;
      int ss = slot ^ (row & 7);
      gload_lds16(A + (size_t)(m0 + row) * (size_t)lda + k0 + ss * 8,
                  &sA[buf][c * 8]);
    }
#pragma unroll
    for (int it = 0; it < (BN * 8) / NTHR; ++it) {
      int c = it * NTHR + tid;
      int row = c >> 3, slot = c & 7;
      int ss = slot ^ (row & 7);
      gload_lds16(Bt + (size_t)(n0 + row) * (size_t)ldb + k0 + ss * 8,
                  &sB[buf][c * 8]);
    }
  };

  const int nk = K >> 6;
  stage(0, 0);
  __syncthreads();
  for (int ki = 0; ki < nk; ++ki) {
    if (ki + 1 < nk) stage((ki + 1) & 1, (ki + 1) << 6);
    const bf16_t* cA = sA[ki & 1];
    const bf16_t* cB = sB[ki & 1];
#pragma unroll
    for (int kk = 0; kk < 2; ++kk) {
      const int s = kk * 4 + (lane >> 4);
      bf16x8 af[4], bfr[4];
#pragma unroll
      for (int i = 0; i < 4; ++i) {
        const int arow = wr * 64 + i * 16 + (lane & 15);
        af[i] = *(const bf16x8*)&cA[arow * 64 + ((s ^ (arow & 7)) * 8)];
        const int brow = wc * 64 + i * 16 + (lane & 15);
        bfr[i] = *(const bf16x8*)&cB[brow * 64 + ((s ^ (brow & 7)) * 8)];
      }
#pragma unroll
      for (int mi = 0; mi < 4; ++mi)
#pragma unroll
        for (int ni = 0; ni < 4; ++ni)
          acc[mi][ni] = __builtin_amdgcn_mfma_f32_16x16x32_bf16(af[mi], bfr[ni], acc[mi][ni], 0, 0, 0);
    }
    __syncthreads();
  }

  float* Cf = (float*)Cv;
  bf16_t* Cb = (bf16_t*)Cv;
  const long long zc = (long long)blockIdx.z * sCz;
#pragma unroll
  for (int mi = 0; mi < 4; ++mi) {
    const int rbase = m0 + wr * 64 + mi * 16 + ((lane >> 4) * 4);
#pragma unroll
    for (int ni = 0; ni < 4; ++ni) {
      const int col = n0 + wc * 64 + ni * 16 + (lane & 15);
      const float bv = bias ? bias[col] : 0.f;
      bf16x4 vloc;
#pragma unroll
      for (int r = 0; r < 4; ++r) {
        const int row = rbase + r;
        float v = acc[mi][ni][r] * alpha + bv;
        if (EPIL == 1) v = 0.5f * v * (1.f + erff(v * 0.70710678118654752f));
        if (resid) v += resid[(long long)blockIdx.z * sRz + (size_t)row * ldc + col];
        const size_t idx = (size_t)(zc + (long long)row * ldc + col);
        if (OBF16) {
          const bf16_t bvv = (bf16_t)v;
          Cb[idx] = bvv;
          if (VT) vloc[r] = bvv;
        } else {
          Cf[idx] = v;
        }
      }
      if (VT && col >= 1536)
        *(bf16x4*)&vt[(size_t)(col - 1536) * 2048 + rbase] = vloc;
    }
  }
}

// ------------------------------------------------- fused flash attention
// 4 waves x 16 Q-rows (Q-tile 64). Causal KV-split parts of <=4 K-tiles
// (TPW=4, 8 slots): 1728 valid blocks (~6.75/CU), longest chain 4 tiles.
// The LAST part (part == qt>>2) also folds in the future-band via MFMA.
// No max-shift exp. T5 setprio. Ouc partials stored in BF16.
#define FLASH_TPW 4
#define FLASH_NSLOT 8
__global__ __launch_bounds__(256) void flash_kernel(
    const bf16_t* __restrict__ qkv, const bf16_t* __restrict__ vT,
    const bf16_t* __restrict__ fkT, const bf16_t* __restrict__ fvT,
    const float* __restrict__ fk_b, bf16_t* __restrict__ Ouc,
    float* __restrict__ lsum) {
  const int qt = 31 - (int)blockIdx.x, h = blockIdx.y, part = blockIdx.z;
  const int ntiles = qt + 1;
  const int q0 = qt << 6;
  const int kt0 = part * FLASH_TPW;
  if (kt0 >= ntiles) return;
  const int kt1 = min(kt0 + FLASH_TPW, ntiles);
  const bool has_band = (part == (qt >> 2));
  const int tid = threadIdx.x, lane = tid & 63, w = tid >> 6;
  __shared__ alignas(16) bf16_t sK[2][64 * 64];
  __shared__ alignas(16) bf16_t sV[2][64 * 64];
  __shared__ alignas(16) bf16_t sP[4][16 * 128];  // 16 rows x 256B, XOR-swz

  const int l15 = lane & 15, l4 = lane >> 4;
  const int rloc = w * 16 + (l4 << 2);  // C-layout row within q-tile (+r)
  const int rowC0 = q0 + rloc;
  bf16_t* sPw = sP[w];

  const int qrow = q0 + w * 16 + l15;
  bf16x8 aq[2];
#pragma unroll
  for (int kk = 0; kk < 2; ++kk)
    aq[kk] = *(const bf16x8*)&qkv[(size_t)qrow * 2304 + h * 64 + 8 * l4 + 32 * kk];

  f32x4 o[4] = {};
  float lacc[4] = {0.f, 0.f, 0.f, 0.f};

  // ---------------- causal tiles
  auto stage = [&](int buf, int kt) {
    const int t0 = kt << 6;
#pragma unroll
    for (int it = 0; it < 2; ++it) {
      const int c = it * 256 + tid;
      const int row = c >> 3, slot = c & 7;
      const int ss = slot ^ (row & 7);
      gload_lds16(qkv + (size_t)(t0 + row) * 2304 + 768 + h * 64 + ss * 8,
                  &sK[buf][c * 8]);
      gload_lds16(vT + ((size_t)h * 64 + row) * 2048 + t0 + ss * 8,
                  &sV[buf][c * 8]);
    }
  };

  stage(0, kt0);
  __syncthreads();

  for (int kt = kt0; kt < kt1; ++kt) {
    const int buf = (kt - kt0) & 1;
    if (kt + 1 < kt1) stage(buf ^ 1, kt + 1);
    const int t0 = kt << 6;

    f32x4 s[4] = {};
    __builtin_amdgcn_s_setprio(1);
#pragma unroll
    for (int kk = 0; kk < 2; ++kk)
#pragma unroll
      for (int ni = 0; ni < 4; ++ni) {
        const int row = ni * 16 + l15;
        const int slot = l4 + 4 * kk;
        bf16x8 bfk = *(const bf16x8*)&sK[buf][row * 64 + ((slot ^ (row & 7)) * 8)];
        s[ni] = __builtin_amdgcn_mfma_f32_16x16x32_bf16(aq[kk], bfk, s[ni], 0, 0, 0);
      }
    __builtin_amdgcn_s_setprio(0);

    const bool full = (t0 + 63 <= q0);
#pragma unroll
    for (int ni = 0; ni < 4; ++ni) {
      const int col = t0 + ni * 16 + l15;
      const int colb = (ni * 16 + l15) * 2;
#pragma unroll
      for (int r = 0; r < 4; ++r) {
        const bool ok = full || (col <= rowC0 + r);
        const float pv = ok ? __expf(s[ni][r] * 0.125f) : 0.f;
        lacc[r] += pv;
        const int pr = (l4 << 2) + r;
        *(bf16_t*)((char*)sPw + ((pr * 256 + colb) ^ ((pr & 7) << 4))) = (bf16_t)pv;
      }
    }

    __builtin_amdgcn_s_setprio(1);
#pragma unroll
    for (int kk = 0; kk < 2; ++kk) {
      const int slot = l4 + 4 * kk;
      bf16x8 ap = *(const bf16x8*)((char*)sPw + (l15 * 256 + ((slot ^ (l15 & 7)) * 16)));
#pragma unroll
      for (int ni = 0; ni < 4; ++ni) {
        const int vrow = ni * 16 + l15;
        bf16x8 bv = *(const bf16x8*)&sV[buf][vrow * 64 + ((slot ^ (vrow & 7)) * 8)];
        o[ni] = __builtin_amdgcn_mfma_f32_16x16x32_bf16(ap, bv, o[ni], 0, 0, 0);
      }
    }
    __builtin_amdgcn_s_setprio(0);
    __syncthreads();
  }

  // ---------------- future-band (folded into the last causal part)
  if (has_band) {
    const int t0 = q0;
    bf16_t* sKb = &sK[0][0];  // 80 rows x 64 (flattened across both buffers)
    bf16_t* sVb = &sV[0][0];  // 64 rows x 128
#pragma unroll
    for (int it = 0; it < 3; ++it) {
      const int c = it * 256 + tid;
      if (c < 640) {
        const int row = c >> 3, slot = c & 7;
        const int ss = slot ^ (row & 7);
        const int srow = min(t0 + row, 2046);
        gload_lds16(fkT + ((size_t)h * 2047 + srow) * 64 + ss * 8, &sKb[c * 8]);
      }
    }
#pragma unroll
    for (int it = 0; it < 4; ++it) {
      const int c = it * 256 + tid;
      const int row = c >> 4, slot = c & 15;
      const int ss = slot ^ (row & 7);
      gload_lds16(fvT + ((size_t)h * 64 + row) * 2048 + t0 + ss * 8, &sVb[c * 8]);
    }
    __syncthreads();

    f32x4 s[6] = {};
    __builtin_amdgcn_s_setprio(1);
#pragma unroll
    for (int kk = 0; kk < 2; ++kk)
#pragma unroll
      for (int ni = 0; ni < 5; ++ni) {
        const int row = ni * 16 + l15;
        const int slot = l4 + 4 * kk;
        bf16x8 bfk = *(const bf16x8*)&sKb[row * 64 + ((slot ^ (row & 7)) * 8)];
        s[ni] = __builtin_amdgcn_mfma_f32_16x16x32_bf16(aq[kk], bfk, s[ni], 0, 0, 0);
      }
    __builtin_amdgcn_s_setprio(0);
    float fkb_v[5];
#pragma unroll
    for (int ni = 0; ni < 5; ++ni)
      fkb_v[ni] = fk_b[h * 2047 + min(t0 + ni * 16 + l15, 2046)];

#pragma unroll
    for (int ni = 0; ni < 6; ++ni) {
      const int c = ni * 16 + l15;
      const int colb = c * 2;
#pragma unroll
      for (int r = 0; r < 4; ++r) {
        const int j = c - (rloc + r);
        const bool ok = (ni < 5) && (j >= 0) && (j < 16) && (t0 + c < 2047);
        const float pv = ok ? __expf((s[ni][r] + fkb_v[ni < 5 ? ni : 0]) * 0.125f) : 0.f;
        lacc[r] += pv;
        const int pr = (l4 << 2) + r;
        *(bf16_t*)((char*)sPw + ((pr * 256 + colb) ^ ((pr & 7) << 4))) = (bf16_t)pv;
      }
    }

    __builtin_amdgcn_s_setprio(1);
#pragma unroll
    for (int kk = 0; kk < 3; ++kk) {
      const int slot = l4 + 4 * kk;
      bf16x8 ap = *(const bf16x8*)((char*)sPw + (l15 * 256 + ((slot ^ (l15 & 7)) * 16)));
#pragma unroll
      for (int ni = 0; ni < 4; ++ni) {
        const int vrow = ni * 16 + l15;
        bf16x8 bv = *(const bf16x8*)&sVb[vrow * 128 + ((slot ^ (vrow & 7)) * 8)];
        o[ni] = __builtin_amdgcn_mfma_f32_16x16x32_bf16(ap, bv, o[ni], 0, 0, 0);
      }
    }
    __builtin_amdgcn_s_setprio(0);
  }

  // epilogue: unnormalized O (bf16) + l (l reduced across the 16 col-lanes)
  bf16_t* Oh = Ouc + (((size_t)h * 32 + qt) * FLASH_NSLOT + part) * 4096;
#pragma unroll
  for (int ni = 0; ni < 4; ++ni) {
    const int col = ni * 16 + l15;
#pragma unroll
    for (int r = 0; r < 4; ++r) Oh[(size_t)(rloc + r) * 64 + col] = (bf16_t)o[ni][r];
  }
#pragma unroll
  for (int off = 1; off < 16; off <<= 1)
#pragma unroll
    for (int r = 0; r < 4; ++r) lacc[r] += __shfl_xor(lacc[r], off);
  if (l15 == 0) {
#pragma unroll
    for (int r = 0; r < 4; ++r)
      lsum[((size_t)h * 2048 + rowC0 + r) * FLASH_NSLOT + part] = lacc[r];
  }
}

// ------------------------------------------------- combine (pure sums)
__global__ __launch_bounds__(256) void combine_kernel(
    const bf16_t* __restrict__ Ouc, const float* __restrict__ lsum,
    const float* __restrict__ fv_b, bf16_t* __restrict__ attn_o) {
  const int t = blockIdx.x * 4 + (threadIdx.x >> 6);
  const int h = blockIdx.y, lane = threadIdx.x & 63;
  const int qt = t >> 6;
  const int nparts = (qt + FLASH_TPW) / FLASH_TPW;  // ceil((qt+1)/TPW)
  const bf16_t* Ob = Ouc + ((size_t)h * 32 + qt) * FLASH_NSLOT * 4096 +
                     (t & 63) * 64 + lane;
  const float* lb = lsum + ((size_t)h * 2048 + t) * FLASH_NSLOT;
  float l_run = 0.f, O_run = 0.f;
  for (int p = 0; p < nparts; ++p) {
    l_run += lb[p];
    O_run += (float)Ob[(size_t)p * 4096];
  }
  const float val = O_run / l_run + fv_b[h * 64 + lane];
  attn_o[(size_t)t * 768 + h * 64 + lane] = (bf16_t)val;
}

// ---------------------------------------------------------------- driver

extern "C" void kernel_launch(void* const* d_in, const int* in_sizes, int n_in,
                              void* d_out, int out_size, void* d_ws, size_t ws_size,
                              hipStream_t stream) {
  (void)in_sizes; (void)n_in; (void)out_size;
  const float* x      = (const float*)d_in[0];
  const float* ln1_w  = (const float*)d_in[1];
  const float* ln1_b  = (const float*)d_in[2];
  const float* attn_w = (const float*)d_in[3];
  const float* attn_b = (const float*)d_in[4];
  const float* fk_w   = (const float*)d_in[5];
  const float* fk_b   = (const float*)d_in[6];
  const float* fv_w   = (const float*)d_in[7];
  const float* fv_b   = (const float*)d_in[8];
  const float* proj_w = (const float*)d_in[9];
  const float* proj_b = (const float*)d_in[10];
  const float* ln2_w  = (const float*)d_in[11];
  const float* ln2_b  = (const float*)d_in[12];
  const float* ff_w1  = (const float*)d_in[13];
  const float* ff_b1  = (const float*)d_in[14];
  const float* ff_w2  = (const float*)d_in[15];
  const float* ff_b2  = (const float*)d_in[16];
  float* out = (float*)d_out;

  char* wsp = (char*)d_ws;
  size_t off = 0;
  auto alloc = [&](size_t bytes) -> void* {
    void* r = wsp + off;
    off += (bytes + 255) & ~(size_t)255;
    return r;
  };

  bf16_t* hbuf    = (bf16_t*)alloc((size_t)2048 * 768 * 2);
  bf16_t* attn_wT = (bf16_t*)alloc((size_t)2304 * 768 * 2);
  bf16_t* proj_wT = (bf16_t*)alloc((size_t)768 * 768 * 2);
  bf16_t* ff_w1T  = (bf16_t*)alloc((size_t)3072 * 768 * 2);
  bf16_t* ff_w2T  = (bf16_t*)alloc((size_t)768 * 3072 * 2);
  bf16_t* fkT     = (bf16_t*)alloc((size_t)12 * 2047 * 64 * 2);
  bf16_t* fvT     = (bf16_t*)alloc(((size_t)12 * 64 * 2048 + 512) * 2);
  bf16_t* qkv     = (bf16_t*)alloc((size_t)2048 * 2304 * 2);
  bf16_t* vT      = (bf16_t*)alloc((size_t)12 * 64 * 2048 * 2);
  bf16_t* attn_o  = (bf16_t*)alloc((size_t)2048 * 768 * 2);
  float*  x2      = (float*)alloc((size_t)2048 * 768 * 4);
  bf16_t* h2      = (bf16_t*)alloc((size_t)2048 * 768 * 2);
  bf16_t* gbuf    = (bf16_t*)alloc((size_t)2048 * 3072 * 2);
  bf16_t* Ouc     = (bf16_t*)alloc((size_t)12 * 32 * FLASH_NSLOT * 4096 * 2);
  float*  lsb     = (float*)alloc((size_t)12 * 2048 * FLASH_NSLOT * 4);

  // split-K partials buffer (bf16, shared by proj then ff2)
  const size_t slice = (size_t)2048 * 768 * 2;  // 3.1 MB (bf16)
  long long remain = ((long long)ws_size - (long long)off) / (long long)slice;
  int KS2 = 6;  // ff2: K=3072; chunks must be multiple of 64 (BK)
  while (KS2 > 1 && ((3072 / KS2) % 64 != 0 || (3072 % KS2) != 0 || KS2 > remain)) --KS2;
  int KS1 = 4;  // proj: K=768
  while (KS1 > 1 && ((768 / KS1) % 64 != 0 || (768 % KS1) != 0 || KS1 > remain)) --KS1;
  int KSmax = KS1 > KS2 ? KS1 : KS2;
  bf16_t* Ppart = (bf16_t*)alloc((size_t)KSmax * slice);

  // 1) prep: LN1 + all 6 weight transposes in ONE launch
  prep_kernel<<<12032, 256, 0, stream>>>(x, ln1_w, ln1_b, hbuf,
                                         attn_w, attn_wT, proj_w, proj_wT,
                                         ff_w1, ff_w1T, ff_w2, ff_w2T,
                                         fk_w, fkT, fv_w, fvT);

  // 2) qkv = h @ attn_w + attn_b, with fused vT write (V region)
  gemm_bt_kernel<2, 2, 0, true, true><<<dim3(18, 16, 1), 256, 0, stream>>>(
      hbuf, 0, 768, attn_wT, 0, 768, qkv, 0, 2304, attn_b, nullptr, 0, vT,
      1.f, 2048, 2304, 768);

  // 3) fused flash attention (TPW=4, 8 slots; band in last part)
  flash_kernel<<<dim3(32, 12, FLASH_NSLOT), 256, 0, stream>>>(
      qkv, vT, fkT, fvT, fk_b, Ouc, lsb);

  // 4) combine (pure sums) -> attn_o
  combine_kernel<<<dim3(512, 12), 256, 0, stream>>>(Ouc, lsb, fv_b, attn_o);

  // 5) proj split-K (bf16 partials)
  {
    const int KC = 768 / KS1;
    gemm_bt_kernel<2, 2, 0, true, false><<<dim3(6, 16, KS1), 256, 0, stream>>>(
        attn_o, KC, 768, proj_wT, KC, 768, Ppart, 2048LL * 768, 768, nullptr,
        nullptr, 0, nullptr, 1.f, 2048, 768, KC);
  }
  // 6) x2 = sum + proj_b + x ; h2 = LN2(x2)   (fused)
  reduce_ln_kernel<<<2048, 256, 0, stream>>>(Ppart, KS1, x, proj_b, x2, h2,
                                             ln2_w, ln2_b);

  // 7) g = gelu(h2 @ ff_w1 + ff_b1)
  gemm_bt_kernel<2, 2, 1, true, false><<<dim3(24, 16, 1), 256, 0, stream>>>(
      h2, 0, 768, ff_w1T, 0, 768, gbuf, 0, 3072, ff_b1, nullptr, 0, nullptr,
      1.f, 2048, 3072, 768);

  // 8) ff2 split-K (bf16 partials)
  {
    const int KC = 3072 / KS2;
    gemm_bt_kernel<2, 2, 0, true, false><<<dim3(6, 16, KS2), 256, 0, stream>>>(
        gbuf, KC, 3072, ff_w2T, KC, 3072, Ppart, 2048LL * 768, 768, nullptr,
        nullptr, 0, nullptr, 1.f, 2048, 768, KC);
  }
  // 9) out = sum + ff_b2 + x2
  reduce_out_kernel<<<2048, 256, 0, stream>>>(Ppart, KS2, x2, ff_b2, out);
}

// Round 18
// 151.451 us; speedup vs baseline: 1.0415x; 1.0415x over previous
//
#include <hip/hip_runtime.h>
#include <math.h>
#include <stdint.h>
#include <stddef.h>

typedef __bf16 bf16_t;
typedef __bf16 bf16x8 __attribute__((ext_vector_type(8)));
typedef __bf16 bf16x4 __attribute__((ext_vector_type(4)));
typedef float f32x4 __attribute__((ext_vector_type(4)));

#define DEV __device__ __forceinline__

// ---------------------------------------------------------------- utilities

DEV void gload_lds16(const void* g, void* l) {
  __builtin_amdgcn_global_load_lds((__attribute__((address_space(1))) void*)g,
                                   (__attribute__((address_space(3))) void*)l,
                                   16, 0, 0);
}

template <bool MAXOP>
DEV float blockReduce256(float v, float* sm) {
  const int lane = threadIdx.x & 63, wid = threadIdx.x >> 6;
#pragma unroll
  for (int o = 32; o > 0; o >>= 1) {
    float ov = __shfl_down(v, o);
    v = MAXOP ? fmaxf(v, ov) : (v + ov);
  }
  if (lane == 0) sm[wid] = v;
  __syncthreads();
  float r = MAXOP ? fmaxf(fmaxf(sm[0], sm[1]), fmaxf(sm[2], sm[3]))
                  : (sm[0] + sm[1] + sm[2] + sm[3]);
  __syncthreads();
  return r;
}

// fast GELU (tanh form, single __expf); |err vs exact| <= ~1e-3
DEV float gelu_fast(float v) {
  const float y = v * (0.79788456080286536f + 0.0356774081363001f * v * v);
  const float e = __expf(2.f * y);
  const float th = 1.f - 2.f / (e + 1.f);
  return 0.5f * v * (1.f + th);
}

// -------------------------------------------------- mega prep kernel
__global__ __launch_bounds__(256) void prep_kernel(
    const float* __restrict__ x, const float* __restrict__ ln1_w,
    const float* __restrict__ ln1_b, bf16_t* __restrict__ hbuf,
    const float* __restrict__ attn_w, bf16_t* __restrict__ attn_wT,
    const float* __restrict__ proj_w, bf16_t* __restrict__ proj_wT,
    const float* __restrict__ ff_w1, bf16_t* __restrict__ ff_w1T,
    const float* __restrict__ ff_w2, bf16_t* __restrict__ ff_w2T,
    const float* __restrict__ fk_w, bf16_t* __restrict__ fkT,
    const float* __restrict__ fv_w, bf16_t* __restrict__ fvT) {
  __shared__ float red[4];
  __shared__ float tile[32][33];
  const int tid = threadIdx.x;
  int bid = blockIdx.x;

  if (bid < 2048) {  // ---- LN1 row
    const float* row = x + (size_t)bid * 768;
    float v[3];
    float s = 0.f;
#pragma unroll
    for (int i = 0; i < 3; ++i) {
      v[i] = row[tid + i * 256];
      s += v[i];
    }
    s = blockReduce256<false>(s, red);
    const float mean = s * (1.f / 768.f);
    float s2 = 0.f;
#pragma unroll
    for (int i = 0; i < 3; ++i) {
      float d = v[i] - mean;
      s2 += d * d;
    }
    s2 = blockReduce256<false>(s2, red);
    const float rstd = rsqrtf(s2 * (1.f / 768.f) + 1e-5f);
#pragma unroll
    for (int i = 0; i < 3; ++i) {
      int c = tid + i * 256;
      hbuf[(size_t)bid * 768 + c] = (bf16_t)((v[i] - mean) * rstd * ln1_w[c] + ln1_b[c]);
    }
    return;
  }
  bid -= 2048;

  const float* in;
  bf16_t* outp;
  int ldin, ldout, R, C, bx, by;
  if (bid < 1728) {
    in = attn_w; outp = attn_wT; ldin = 2304; ldout = 768; R = 768; C = 2304;
    bx = bid % 72; by = bid / 72;
  } else if (bid < 2304) {
    int k = bid - 1728;
    in = proj_w; outp = proj_wT; ldin = 768; ldout = 768; R = 768; C = 768;
    bx = k % 24; by = k / 24;
  } else if (bid < 4608) {
    int k = bid - 2304;
    in = ff_w1; outp = ff_w1T; ldin = 3072; ldout = 768; R = 768; C = 3072;
    bx = k % 96; by = k / 96;
  } else if (bid < 6912) {
    int k = bid - 4608;
    in = ff_w2; outp = ff_w2T; ldin = 768; ldout = 3072; R = 3072; C = 768;
    bx = k % 24; by = k / 24;
  } else if (bid < 8448) {
    int k = bid - 6912;
    int z = k >> 7, r = k & 127;
    in = fk_w + (size_t)z * 64 * 2047; outp = fkT + (size_t)z * 2047 * 64;
    ldin = 2047; ldout = 64; R = 64; C = 2047;
    bx = r % 64; by = r / 64;
  } else {
    int k = bid - 8448;
    int z = k >> 7, r = k & 127;
    in = fv_w + (size_t)z * 2047 * 64; outp = fvT + (size_t)z * 64 * 2048;
    ldin = 64; ldout = 2048; R = 2047; C = 64;
    bx = r % 2; by = r / 2;
  }

  const int tx = tid & 31, ty = tid >> 5;
  const int c0 = bx * 32, r0 = by * 32;
#pragma unroll
  for (int i = 0; i < 4; ++i) {
    int r = r0 + ty + i * 8, c = c0 + tx;
    if (r < R && c < C) tile[ty + i * 8][tx] = in[(size_t)r * ldin + c];
  }
  __syncthreads();
#pragma unroll
  for (int i = 0; i < 4; ++i) {
    int orow = c0 + ty + i * 8, oc = r0 + tx;
    if (orow < C && oc < R) outp[(size_t)orow * ldout + oc] = (bf16_t)tile[tx][ty + i * 8];
  }
}

// ----------------------------------------- split-K reduce + residual + LN2
__global__ __launch_bounds__(256) void reduce_ln_kernel(
    const bf16_t* __restrict__ P, int KS, const float* __restrict__ x,
    const float* __restrict__ pb, float* __restrict__ x2,
    bf16_t* __restrict__ h2, const float* __restrict__ w,
    const float* __restrict__ b) {
  __shared__ float red[4];
  const int t = blockIdx.x, tid = threadIdx.x;
  float v[3];
  float s = 0.f;
#pragma unroll
  for (int i = 0; i < 3; ++i) {
    const int c = tid + i * 256;
    const size_t idx = (size_t)t * 768 + c;
    float a = x[idx] + pb[c];
    for (int ss = 0; ss < KS; ++ss) a += (float)P[(size_t)ss * 2048 * 768 + idx];
    v[i] = a;
    x2[idx] = a;
    s += a;
  }
  s = blockReduce256<false>(s, red);
  const float mean = s * (1.f / 768.f);
  float s2 = 0.f;
#pragma unroll
  for (int i = 0; i < 3; ++i) {
    float d = v[i] - mean;
    s2 += d * d;
  }
  s2 = blockReduce256<false>(s2, red);
  const float rstd = rsqrtf(s2 * (1.f / 768.f) + 1e-5f);
#pragma unroll
  for (int i = 0; i < 3; ++i) {
    int c = tid + i * 256;
    h2[(size_t)t * 768 + c] = (bf16_t)((v[i] - mean) * rstd * w[c] + b[c]);
  }
}

// ----------------------------------------- split-K reduce + residual (out)
__global__ __launch_bounds__(256) void reduce_out_kernel(
    const bf16_t* __restrict__ P, int KS, const float* __restrict__ x2,
    const float* __restrict__ bb, float* __restrict__ out) {
  const int t = blockIdx.x, tid = threadIdx.x;
#pragma unroll
  for (int i = 0; i < 3; ++i) {
    const int c = tid + i * 256;
    const size_t idx = (size_t)t * 768 + c;
    float a = x2[idx] + bb[c];
    for (int ss = 0; ss < KS; ++ss) a += (float)P[(size_t)ss * 2048 * 768 + idx];
    out[idx] = a;
  }
}

// ---------------------------------------------------------------- GEMM (B^T)
// BK=64 K-step, XOR-swizzled staging (rule #21), __syncthreads per step
// (r13-proven structure). Optional fused vT write for the qkv GEMM.
template <int WM, int WN, int EPIL, bool OBF16, bool VT>
__global__ __launch_bounds__(64 * WM * WN) void gemm_bt_kernel(
    const bf16_t* __restrict__ A, long long sAz, int lda,
    const bf16_t* __restrict__ Bt, long long sBz, int ldb,
    void* __restrict__ Cv, long long sCz, int ldc,
    const float* __restrict__ bias,
    const float* __restrict__ resid, long long sRz,
    bf16_t* __restrict__ vt,
    float alpha, int M, int N, int K) {
  constexpr int BM = WM * 64, BN = WN * 64;
  constexpr int NTHR = 64 * WM * WN;
  const int tid = threadIdx.x;
  const int lane = tid & 63, wid = tid >> 6;
  const int wr = wid / WN, wc = wid % WN;
  const int m0 = blockIdx.y * BM, n0 = blockIdx.x * BN;
  A += (long long)blockIdx.z * sAz;
  Bt += (long long)blockIdx.z * sBz;

  __shared__ alignas(16) bf16_t sA[2][BM * 64];
  __shared__ alignas(16) bf16_t sB[2][BN * 64];

  f32x4 acc[4][4] = {};

  auto stage = [&](int buf, int k0) {
#pragma unroll
    for (int it = 0; it < (BM * 8) / NTHR; ++it) {
      int c = it * NTHR + tid;
      int row = c >> 3, slot = c & 7;
      int ss = slot ^ (row & 7);
      gload_lds16(A + (size_t)(m0 + row) * (size_t)lda + k0 + ss * 8,
                  &sA[buf][c * 8]);
    }
#pragma unroll
    for (int it = 0; it < (BN * 8) / NTHR; ++it) {
      int c = it * NTHR + tid;
      int row = c >> 3, slot = c & 7;
      int ss = slot ^ (row & 7);
      gload_lds16(Bt + (size_t)(n0 + row) * (size_t)ldb + k0 + ss * 8,
                  &sB[buf][c * 8]);
    }
  };

  const int nk = K >> 6;
  stage(0, 0);
  __syncthreads();
  for (int ki = 0; ki < nk; ++ki) {
    if (ki + 1 < nk) stage((ki + 1) & 1, (ki + 1) << 6);
    const bf16_t* cA = sA[ki & 1];
    const bf16_t* cB = sB[ki & 1];
#pragma unroll
    for (int kk = 0; kk < 2; ++kk) {
      const int s = kk * 4 + (lane >> 4);
      bf16x8 af[4], bfr[4];
#pragma unroll
      for (int i = 0; i < 4; ++i) {
        const int arow = wr * 64 + i * 16 + (lane & 15);
        af[i] = *(const bf16x8*)&cA[arow * 64 + ((s ^ (arow & 7)) * 8)];
        const int brow = wc * 64 + i * 16 + (lane & 15);
        bfr[i] = *(const bf16x8*)&cB[brow * 64 + ((s ^ (brow & 7)) * 8)];
      }
#pragma unroll
      for (int mi = 0; mi < 4; ++mi)
#pragma unroll
        for (int ni = 0; ni < 4; ++ni)
          acc[mi][ni] = __builtin_amdgcn_mfma_f32_16x16x32_bf16(af[mi], bfr[ni], acc[mi][ni], 0, 0, 0);
    }
    __syncthreads();
  }

  float* Cf = (float*)Cv;
  bf16_t* Cb = (bf16_t*)Cv;
  const long long zc = (long long)blockIdx.z * sCz;
#pragma unroll
  for (int mi = 0; mi < 4; ++mi) {
    const int rbase = m0 + wr * 64 + mi * 16 + ((lane >> 4) * 4);
#pragma unroll
    for (int ni = 0; ni < 4; ++ni) {
      const int col = n0 + wc * 64 + ni * 16 + (lane & 15);
      const float bv = bias ? bias[col] : 0.f;
      bf16x4 vloc;
#pragma unroll
      for (int r = 0; r < 4; ++r) {
        const int row = rbase + r;
        float v = acc[mi][ni][r] * alpha + bv;
        if (EPIL == 1) v = gelu_fast(v);
        if (resid) v += resid[(long long)blockIdx.z * sRz + (size_t)row * ldc + col];
        const size_t idx = (size_t)(zc + (long long)row * ldc + col);
        if (OBF16) {
          const bf16_t bvv = (bf16_t)v;
          Cb[idx] = bvv;
          if (VT) vloc[r] = bvv;
        } else {
          Cf[idx] = v;
        }
      }
      if (VT && col >= 1536)
        *(bf16x4*)&vt[(size_t)(col - 1536) * 2048 + rbase] = vloc;
    }
  }
}

// ------------------------------------------------- fused flash attention
// 4 waves x 16 Q-rows (Q-tile 64). Causal KV-split parts of <=8 K-tiles;
// the LAST part (part == qt>>3) also folds in the future-band via MFMA
// (plain-sum softmax makes the band additive). No max-shift exp. T5 setprio.
// Ouc partials stored in BF16.
#define FLASH_TPW 8
#define FLASH_NSLOT 4
__global__ __launch_bounds__(256) void flash_kernel(
    const bf16_t* __restrict__ qkv, const bf16_t* __restrict__ vT,
    const bf16_t* __restrict__ fkT, const bf16_t* __restrict__ fvT,
    const float* __restrict__ fk_b, bf16_t* __restrict__ Ouc,
    float* __restrict__ lsum) {
  const int qt = 31 - (int)blockIdx.x, h = blockIdx.y, part = blockIdx.z;
  const int ntiles = qt + 1;
  const int q0 = qt << 6;
  const int kt0 = part * FLASH_TPW;
  if (kt0 >= ntiles) return;
  const int kt1 = min(kt0 + FLASH_TPW, ntiles);
  const bool has_band = (part == (qt >> 3));
  const int tid = threadIdx.x, lane = tid & 63, w = tid >> 6;
  __shared__ alignas(16) bf16_t sK[2][64 * 64];
  __shared__ alignas(16) bf16_t sV[2][64 * 64];
  __shared__ alignas(16) bf16_t sP[4][16 * 128];  // 16 rows x 256B, XOR-swz

  const int l15 = lane & 15, l4 = lane >> 4;
  const int rloc = w * 16 + (l4 << 2);  // C-layout row within q-tile (+r)
  const int rowC0 = q0 + rloc;
  bf16_t* sPw = sP[w];

  const int qrow = q0 + w * 16 + l15;
  bf16x8 aq[2];
#pragma unroll
  for (int kk = 0; kk < 2; ++kk)
    aq[kk] = *(const bf16x8*)&qkv[(size_t)qrow * 2304 + h * 64 + 8 * l4 + 32 * kk];

  f32x4 o[4] = {};
  float lacc[4] = {0.f, 0.f, 0.f, 0.f};

  // ---------------- causal tiles
  auto stage = [&](int buf, int kt) {
    const int t0 = kt << 6;
#pragma unroll
    for (int it = 0; it < 2; ++it) {
      const int c = it * 256 + tid;
      const int row = c >> 3, slot = c & 7;
      const int ss = slot ^ (row & 7);
      gload_lds16(qkv + (size_t)(t0 + row) * 2304 + 768 + h * 64 + ss * 8,
                  &sK[buf][c * 8]);
      gload_lds16(vT + ((size_t)h * 64 + row) * 2048 + t0 + ss * 8,
                  &sV[buf][c * 8]);
    }
  };

  stage(0, kt0);
  __syncthreads();

  for (int kt = kt0; kt < kt1; ++kt) {
    const int buf = (kt - kt0) & 1;
    if (kt + 1 < kt1) stage(buf ^ 1, kt + 1);
    const int t0 = kt << 6;

    f32x4 s[4] = {};
    __builtin_amdgcn_s_setprio(1);
#pragma unroll
    for (int kk = 0; kk < 2; ++kk)
#pragma unroll
      for (int ni = 0; ni < 4; ++ni) {
        const int row = ni * 16 + l15;
        const int slot = l4 + 4 * kk;
        bf16x8 bfk = *(const bf16x8*)&sK[buf][row * 64 + ((slot ^ (row & 7)) * 8)];
        s[ni] = __builtin_amdgcn_mfma_f32_16x16x32_bf16(aq[kk], bfk, s[ni], 0, 0, 0);
      }
    __builtin_amdgcn_s_setprio(0);

    const bool full = (t0 + 63 <= q0);
#pragma unroll
    for (int ni = 0; ni < 4; ++ni) {
      const int col = t0 + ni * 16 + l15;
      const int colb = (ni * 16 + l15) * 2;
#pragma unroll
      for (int r = 0; r < 4; ++r) {
        const bool ok = full || (col <= rowC0 + r);
        const float pv = ok ? __expf(s[ni][r] * 0.125f) : 0.f;
        lacc[r] += pv;
        const int pr = (l4 << 2) + r;
        *(bf16_t*)((char*)sPw + ((pr * 256 + colb) ^ ((pr & 7) << 4))) = (bf16_t)pv;
      }
    }

    __builtin_amdgcn_s_setprio(1);
#pragma unroll
    for (int kk = 0; kk < 2; ++kk) {
      const int slot = l4 + 4 * kk;
      bf16x8 ap = *(const bf16x8*)((char*)sPw + (l15 * 256 + ((slot ^ (l15 & 7)) * 16)));
#pragma unroll
      for (int ni = 0; ni < 4; ++ni) {
        const int vrow = ni * 16 + l15;
        bf16x8 bv = *(const bf16x8*)&sV[buf][vrow * 64 + ((slot ^ (vrow & 7)) * 8)];
        o[ni] = __builtin_amdgcn_mfma_f32_16x16x32_bf16(ap, bv, o[ni], 0, 0, 0);
      }
    }
    __builtin_amdgcn_s_setprio(0);
    __syncthreads();
  }

  // ---------------- future-band (folded into the last causal part)
  if (has_band) {
    const int t0 = q0;
    bf16_t* sKb = &sK[0][0];  // 80 rows x 64 (flattened across both buffers)
    bf16_t* sVb = &sV[0][0];  // 64 rows x 128
#pragma unroll
    for (int it = 0; it < 3; ++it) {
      const int c = it * 256 + tid;
      if (c < 640) {
        const int row = c >> 3, slot = c & 7;
        const int ss = slot ^ (row & 7);
        const int srow = min(t0 + row, 2046);
        gload_lds16(fkT + ((size_t)h * 2047 + srow) * 64 + ss * 8, &sKb[c * 8]);
      }
    }
#pragma unroll
    for (int it = 0; it < 4; ++it) {
      const int c = it * 256 + tid;
      const int row = c >> 4, slot = c & 15;
      const int ss = slot ^ (row & 7);
      gload_lds16(fvT + ((size_t)h * 64 + row) * 2048 + t0 + ss * 8, &sVb[c * 8]);
    }
    __syncthreads();

    f32x4 s[6] = {};
    __builtin_amdgcn_s_setprio(1);
#pragma unroll
    for (int kk = 0; kk < 2; ++kk)
#pragma unroll
      for (int ni = 0; ni < 5; ++ni) {
        const int row = ni * 16 + l15;
        const int slot = l4 + 4 * kk;
        bf16x8 bfk = *(const bf16x8*)&sKb[row * 64 + ((slot ^ (row & 7)) * 8)];
        s[ni] = __builtin_amdgcn_mfma_f32_16x16x32_bf16(aq[kk], bfk, s[ni], 0, 0, 0);
      }
    __builtin_amdgcn_s_setprio(0);
    float fkb_v[5];
#pragma unroll
    for (int ni = 0; ni < 5; ++ni)
      fkb_v[ni] = fk_b[h * 2047 + min(t0 + ni * 16 + l15, 2046)];

#pragma unroll
    for (int ni = 0; ni < 6; ++ni) {
      const int c = ni * 16 + l15;
      const int colb = c * 2;
#pragma unroll
      for (int r = 0; r < 4; ++r) {
        const int j = c - (rloc + r);
        const bool ok = (ni < 5) && (j >= 0) && (j < 16) && (t0 + c < 2047);
        const float pv = ok ? __expf((s[ni][r] + fkb_v[ni < 5 ? ni : 0]) * 0.125f) : 0.f;
        lacc[r] += pv;
        const int pr = (l4 << 2) + r;
        *(bf16_t*)((char*)sPw + ((pr * 256 + colb) ^ ((pr & 7) << 4))) = (bf16_t)pv;
      }
    }

    __builtin_amdgcn_s_setprio(1);
#pragma unroll
    for (int kk = 0; kk < 3; ++kk) {
      const int slot = l4 + 4 * kk;
      bf16x8 ap = *(const bf16x8*)((char*)sPw + (l15 * 256 + ((slot ^ (l15 & 7)) * 16)));
#pragma unroll
      for (int ni = 0; ni < 4; ++ni) {
        const int vrow = ni * 16 + l15;
        bf16x8 bv = *(const bf16x8*)&sVb[vrow * 128 + ((slot ^ (vrow & 7)) * 8)];
        o[ni] = __builtin_amdgcn_mfma_f32_16x16x32_bf16(ap, bv, o[ni], 0, 0, 0);
      }
    }
    __builtin_amdgcn_s_setprio(0);
  }

  // epilogue: unnormalized O (bf16) + l (l reduced across the 16 col-lanes)
  bf16_t* Oh = Ouc + (((size_t)h * 32 + qt) * FLASH_NSLOT + part) * 4096;
#pragma unroll
  for (int ni = 0; ni < 4; ++ni) {
    const int col = ni * 16 + l15;
#pragma unroll
    for (int r = 0; r < 4; ++r) Oh[(size_t)(rloc + r) * 64 + col] = (bf16_t)o[ni][r];
  }
#pragma unroll
  for (int off = 1; off < 16; off <<= 1)
#pragma unroll
    for (int r = 0; r < 4; ++r) lacc[r] += __shfl_xor(lacc[r], off);
  if (l15 == 0) {
#pragma unroll
    for (int r = 0; r < 4; ++r)
      lsum[((size_t)h * 2048 + rowC0 + r) * FLASH_NSLOT + part] = lacc[r];
  }
}

// ------------------------------------------------- combine (pure sums)
__global__ __launch_bounds__(256) void combine_kernel(
    const bf16_t* __restrict__ Ouc, const float* __restrict__ lsum,
    const float* __restrict__ fv_b, bf16_t* __restrict__ attn_o) {
  const int t = blockIdx.x * 4 + (threadIdx.x >> 6);
  const int h = blockIdx.y, lane = threadIdx.x & 63;
  const int qt = t >> 6;
  const int nparts = (qt + FLASH_TPW) / FLASH_TPW;  // ceil((qt+1)/8)
  const bf16_t* Ob = Ouc + ((size_t)h * 32 + qt) * FLASH_NSLOT * 4096 +
                     (t & 63) * 64 + lane;
  const float* lb = lsum + ((size_t)h * 2048 + t) * FLASH_NSLOT;
  float l_run = 0.f, O_run = 0.f;
  for (int p = 0; p < nparts; ++p) {
    l_run += lb[p];
    O_run += (float)Ob[(size_t)p * 4096];
  }
  const float val = O_run / l_run + fv_b[h * 64 + lane];
  attn_o[(size_t)t * 768 + h * 64 + lane] = (bf16_t)val;
}

// ---------------------------------------------------------------- driver

extern "C" void kernel_launch(void* const* d_in, const int* in_sizes, int n_in,
                              void* d_out, int out_size, void* d_ws, size_t ws_size,
                              hipStream_t stream) {
  (void)in_sizes; (void)n_in; (void)out_size;
  const float* x      = (const float*)d_in[0];
  const float* ln1_w  = (const float*)d_in[1];
  const float* ln1_b  = (const float*)d_in[2];
  const float* attn_w = (const float*)d_in[3];
  const float* attn_b = (const float*)d_in[4];
  const float* fk_w   = (const float*)d_in[5];
  const float* fk_b   = (const float*)d_in[6];
  const float* fv_w   = (const float*)d_in[7];
  const float* fv_b   = (const float*)d_in[8];
  const float* proj_w = (const float*)d_in[9];
  const float* proj_b = (const float*)d_in[10];
  const float* ln2_w  = (const float*)d_in[11];
  const float* ln2_b  = (const float*)d_in[12];
  const float* ff_w1  = (const float*)d_in[13];
  const float* ff_b1  = (const float*)d_in[14];
  const float* ff_w2  = (const float*)d_in[15];
  const float* ff_b2  = (const float*)d_in[16];
  float* out = (float*)d_out;

  char* wsp = (char*)d_ws;
  size_t off = 0;
  auto alloc = [&](size_t bytes) -> void* {
    void* r = wsp + off;
    off += (bytes + 255) & ~(size_t)255;
    return r;
  };

  bf16_t* hbuf    = (bf16_t*)alloc((size_t)2048 * 768 * 2);
  bf16_t* attn_wT = (bf16_t*)alloc((size_t)2304 * 768 * 2);
  bf16_t* proj_wT = (bf16_t*)alloc((size_t)768 * 768 * 2);
  bf16_t* ff_w1T  = (bf16_t*)alloc((size_t)3072 * 768 * 2);
  bf16_t* ff_w2T  = (bf16_t*)alloc((size_t)768 * 3072 * 2);
  bf16_t* fkT     = (bf16_t*)alloc((size_t)12 * 2047 * 64 * 2);
  bf16_t* fvT     = (bf16_t*)alloc(((size_t)12 * 64 * 2048 + 512) * 2);
  bf16_t* qkv     = (bf16_t*)alloc((size_t)2048 * 2304 * 2);
  bf16_t* vT      = (bf16_t*)alloc((size_t)12 * 64 * 2048 * 2);
  bf16_t* attn_o  = (bf16_t*)alloc((size_t)2048 * 768 * 2);
  float*  x2      = (float*)alloc((size_t)2048 * 768 * 4);
  bf16_t* h2      = (bf16_t*)alloc((size_t)2048 * 768 * 2);
  bf16_t* gbuf    = (bf16_t*)alloc((size_t)2048 * 3072 * 2);
  bf16_t* Ouc     = (bf16_t*)alloc((size_t)12 * 32 * FLASH_NSLOT * 4096 * 2);
  float*  lsb     = (float*)alloc((size_t)12 * 2048 * FLASH_NSLOT * 4);

  // split-K partials buffer (bf16, shared by proj then ff2)
  const size_t slice = (size_t)2048 * 768 * 2;  // 3.1 MB (bf16)
  long long remain = ((long long)ws_size - (long long)off) / (long long)slice;
  int KS2 = 6;  // ff2: K=3072; chunks must be multiple of 64 (BK)
  while (KS2 > 1 && ((3072 / KS2) % 64 != 0 || (3072 % KS2) != 0 || KS2 > remain)) --KS2;
  int KS1 = 4;  // proj: K=768
  while (KS1 > 1 && ((768 / KS1) % 64 != 0 || (768 % KS1) != 0 || KS1 > remain)) --KS1;
  int KSmax = KS1 > KS2 ? KS1 : KS2;
  bf16_t* Ppart = (bf16_t*)alloc((size_t)KSmax * slice);

  // 1) prep: LN1 + all 6 weight transposes in ONE launch
  prep_kernel<<<12032, 256, 0, stream>>>(x, ln1_w, ln1_b, hbuf,
                                         attn_w, attn_wT, proj_w, proj_wT,
                                         ff_w1, ff_w1T, ff_w2, ff_w2T,
                                         fk_w, fkT, fv_w, fvT);

  // 2) qkv = h @ attn_w + attn_b, with fused vT write (V region)
  gemm_bt_kernel<2, 2, 0, true, true><<<dim3(18, 16, 1), 256, 0, stream>>>(
      hbuf, 0, 768, attn_wT, 0, 768, qkv, 0, 2304, attn_b, nullptr, 0, vT,
      1.f, 2048, 2304, 768);

  // 3) fused flash attention (band folded into last causal part)
  flash_kernel<<<dim3(32, 12, FLASH_NSLOT), 256, 0, stream>>>(
      qkv, vT, fkT, fvT, fk_b, Ouc, lsb);

  // 4) combine (pure sums) -> attn_o
  combine_kernel<<<dim3(512, 12), 256, 0, stream>>>(Ouc, lsb, fv_b, attn_o);

  // 5) proj split-K (bf16 partials)
  {
    const int KC = 768 / KS1;
    gemm_bt_kernel<2, 2, 0, true, false><<<dim3(6, 16, KS1), 256, 0, stream>>>(
        attn_o, KC, 768, proj_wT, KC, 768, Ppart, 2048LL * 768, 768, nullptr,
        nullptr, 0, nullptr, 1.f, 2048, 768, KC);
  }
  // 6) x2 = sum + proj_b + x ; h2 = LN2(x2)   (fused)
  reduce_ln_kernel<<<2048, 256, 0, stream>>>(Ppart, KS1, x, proj_b, x2, h2,
                                             ln2_w, ln2_b);

  // 7) g = gelu(h2 @ ff_w1 + ff_b1)   (fast tanh-form GELU)
  gemm_bt_kernel<2, 2, 1, true, false><<<dim3(24, 16, 1), 256, 0, stream>>>(
      h2, 0, 768, ff_w1T, 0, 768, gbuf, 0, 3072, ff_b1, nullptr, 0, nullptr,
      1.f, 2048, 3072, 768);

  // 8) ff2 split-K (bf16 partials)
  {
    const int KC = 3072 / KS2;
    gemm_bt_kernel<2, 2, 0, true, false><<<dim3(6, 16, KS2), 256, 0, stream>>>(
        gbuf, KC, 3072, ff_w2T, KC, 3072, Ppart, 2048LL * 768, 768, nullptr,
        nullptr, 0, nullptr, 1.f, 2048, 768, KC);
  }
  // 9) out = sum + ff_b2 + x2
  reduce_out_kernel<<<2048, 256, 0, stream>>>(Ppart, KS2, x2, ff_b2, out);
}